// Round 3
// baseline (28349.313 us; speedup 1.0000x reference)
//
#include <hip/hip_runtime.h>
#include <hip/hip_bf16.h>

#define T_STEPS 512
#define BATCH   256
#define HID     100
#define GATES   400   // 4*H
#define BT      (BATCH * T_STEPS)

__device__ __forceinline__ float sigm_f(float x) {
    return 1.f / (1.f + __expf(-x));
}

__device__ __forceinline__ float tanh_f(float x) {
    float ax = fabsf(x);
    float t  = __expf(-2.f * ax);
    float r  = (1.f - t) / (1.f + t);
    return copysignf(r, x);
}

// ---------------------------------------------------------------------------
// xg GEMM: out[row, g] = sum_k A[src_row, k] * W[g, k] + b1[g] + b2[g]
// rows = B*T (M=131072), cols = 400 padded to 4 tiles of 128.
// BM=128, BN=128, BK=20. 256 threads, 8x8 microtile, strided ownership:
//   thread rows = row0 + ty + 16*r   (r=0..7)   ty = tid>>4
//   thread cols = col0 + tx + 16*j   (j=0..7)   tx = tid&15
// Bank math: row stride 20 floats (80B, 16B-aligned). a-reads: 4 distinct
// rows/wave -> banks 0/20/8/28 (clean). b-reads: 16 rows/wave -> 2-way (free).
// Live regs: acc 64 + a4 32 + b4 4 + addr ~15 -> fits 128 VGPR, 4 waves/SIMD.
// ---------------------------------------------------------------------------
template <int K, bool GATHER>
__global__ __launch_bounds__(256, 4) void xg_gemm(
    const float* __restrict__ A, const int* __restrict__ idx,
    const float* __restrict__ W, const float* __restrict__ b1,
    const float* __restrict__ b2, float* __restrict__ out)
{
    __shared__ float As[128][20];
    __shared__ float Bs[128][20];
    __shared__ int   idx_s[128];

    const int tid  = threadIdx.x;
    const int tx   = tid & 15;
    const int ty   = tid >> 4;
    const int row0 = blockIdx.x * 128;
    const int col0 = blockIdx.y * 128;

    if (GATHER) {
        if (tid < 128) idx_s[tid] = idx[row0 + tid];
    }

    float acc[8][8];
#pragma unroll
    for (int r = 0; r < 8; ++r)
#pragma unroll
        for (int j = 0; j < 8; ++j) acc[r][j] = 0.f;

#pragma unroll 1
    for (int k0 = 0; k0 < K; k0 += 20) {
        __syncthreads();
        // stage A tile: 128 rows x 20 floats = 640 float4
        for (int e = tid; e < 640; e += 256) {
            int r = e / 5, kq = e % 5;
            int src_row = GATHER ? idx_s[r] : (row0 + r);
            float4 v = *(const float4*)(A + (size_t)src_row * K + k0 + kq * 4);
            *(float4*)(&As[r][kq * 4]) = v;
        }
        // stage W tile: 128 gate-rows x 20 floats, guard rows >= 400
        for (int e = tid; e < 640; e += 256) {
            int r = e / 5, kq = e % 5;
            int wrow = col0 + r;
            float4 v = make_float4(0.f, 0.f, 0.f, 0.f);
            if (wrow < GATES)
                v = *(const float4*)(W + (size_t)wrow * K + k0 + kq * 4);
            *(float4*)(&Bs[r][kq * 4]) = v;
        }
        __syncthreads();

#pragma unroll
        for (int kk = 0; kk < 20; kk += 4) {
            float4 a4[8];
#pragma unroll
            for (int r = 0; r < 8; ++r)
                a4[r] = *(const float4*)(&As[ty + 16 * r][kk]);
#pragma unroll
            for (int j = 0; j < 8; ++j) {
                float4 b4 = *(const float4*)(&Bs[tx + 16 * j][kk]);
#pragma unroll
                for (int r = 0; r < 8; ++r) {
                    acc[r][j] += a4[r].x * b4.x + a4[r].y * b4.y +
                                 a4[r].z * b4.z + a4[r].w * b4.w;
                }
            }
        }
    }

    // epilogue: bias + guarded store
    float bias[8];
#pragma unroll
    for (int j = 0; j < 8; ++j) {
        int col = col0 + tx + 16 * j;
        bias[j] = (col < GATES) ? (b1[col] + b2[col]) : 0.f;
    }
#pragma unroll
    for (int r = 0; r < 8; ++r) {
        int row = row0 + ty + 16 * r;
#pragma unroll
        for (int j = 0; j < 8; ++j) {
            int col = col0 + tx + 16 * j;
            if (col < GATES)
                out[(size_t)row * GATES + col] = acc[r][j] + bias[j];
        }
    }
}

// ---------------------------------------------------------------------------
// Recurrent scan for one layer. One block per batch element; 448 threads,
// threads g<400 each own one gate row of W_hh (100 floats in VGPRs).
// ---------------------------------------------------------------------------
__global__ __launch_bounds__(448) void lstm_recur(
    const float* __restrict__ xg,    // [B, T, 400]
    const float* __restrict__ w_hh,  // [400, 100]
    const int*   __restrict__ lengths,
    float* __restrict__ hs)          // [B, T, 100]
{
    const int b = blockIdx.x;
    const int g = threadIdx.x;

    __shared__ float h_s[HID];
    __shared__ float gate_s[GATES];

    float w[HID];
    if (g < GATES) {
#pragma unroll
        for (int k = 0; k < HID; k += 4) {
            float4 t = *(const float4*)(w_hh + (size_t)g * HID + k);
            w[k] = t.x; w[k + 1] = t.y; w[k + 2] = t.z; w[k + 3] = t.w;
        }
    }
    if (g < HID) h_s[g] = 0.f;
    float c_reg = 0.f;
    float h_reg = 0.f;

    const int len = lengths[b];
    const float* xgb = xg + (size_t)b * T_STEPS * GATES;
    float*       hsb = hs + (size_t)b * T_STEPS * HID;

    float xg_cur = (g < GATES) ? xgb[g] : 0.f;
    __syncthreads();

    for (int t = 0; t < T_STEPS; ++t) {
        float xg_next = 0.f;
        if (g < GATES && t + 1 < T_STEPS) xg_next = xgb[(size_t)(t + 1) * GATES + g];

        if (g < GATES) {
            float s0 = 0.f, s1 = 0.f, s2 = 0.f, s3 = 0.f;
#pragma unroll
            for (int k = 0; k < HID; k += 4) {
                float4 h4 = *(const float4*)(&h_s[k]);
                s0 += w[k]     * h4.x;
                s1 += w[k + 1] * h4.y;
                s2 += w[k + 2] * h4.z;
                s3 += w[k + 3] * h4.w;
            }
            float pre = xg_cur + ((s0 + s1) + (s2 + s3));
            float a = (g >= 200 && g < 300) ? tanh_f(pre) : sigm_f(pre);
            gate_s[g] = a;
        }
        __syncthreads();
        if (g < HID) {
            float iv = gate_s[g];
            float fv = gate_s[HID + g];
            float gv = gate_s[2 * HID + g];
            float ov = gate_s[3 * HID + g];
            float c_new = fv * c_reg + iv * gv;
            float h_new = ov * tanh_f(c_new);
            bool m = (t < len);
            c_reg = m ? c_new : c_reg;
            h_reg = m ? h_new : h_reg;
            h_s[g] = h_reg;
            hsb[(size_t)t * HID + g] = h_reg;
        }
        xg_cur = xg_next;
        __syncthreads();
    }
}

// ---------------------------------------------------------------------------
// Final linear head
// ---------------------------------------------------------------------------
__global__ __launch_bounds__(64) void fc_kernel(
    const float* __restrict__ hs, const float* __restrict__ w_fc,
    const float* __restrict__ b_fc, float* __restrict__ out)
{
    int tid = blockIdx.x * 64 + threadIdx.x;
    if (tid >= BATCH * 3) return;
    int b = tid / 3, o = tid % 3;
    const float* h = hs + ((size_t)b * T_STEPS + (T_STEPS - 1)) * HID;
    float acc = b_fc[o];
    for (int j = 0; j < HID; ++j) acc += h[j] * w_fc[o * HID + j];
    out[b * 3 + o] = acc;
}

extern "C" void kernel_launch(void* const* d_in, const int* in_sizes, int n_in,
                              void* d_out, int out_size, void* d_ws, size_t ws_size,
                              hipStream_t stream)
{
    const int*   x       = (const int*)  d_in[0];
    const int*   lengths = (const int*)  d_in[1];
    const float* emb     = (const float*)d_in[2];
    const float* w_ih0   = (const float*)d_in[3];
    const float* w_hh0   = (const float*)d_in[4];
    const float* b_ih0   = (const float*)d_in[5];
    const float* b_hh0   = (const float*)d_in[6];
    const float* w_ih1   = (const float*)d_in[7];
    const float* w_hh1   = (const float*)d_in[8];
    const float* b_ih1   = (const float*)d_in[9];
    const float* b_hh1   = (const float*)d_in[10];
    const float* w_ih2   = (const float*)d_in[11];
    const float* w_hh2   = (const float*)d_in[12];
    const float* b_ih2   = (const float*)d_in[13];
    const float* b_hh2   = (const float*)d_in[14];
    const float* w_fc    = (const float*)d_in[15];
    const float* b_fc    = (const float*)d_in[16];
    float* out = (float*)d_out;

    float* xg = (float*)d_ws;                  // [BT, 400]  ~210 MB
    float* hs = xg + (size_t)BT * GATES;       // [BT, 100]  ~52 MB

    dim3 ggrid(BT / 128, 4);

    // Layer 0: embedding gather fused into A-stage, K=300
    xg_gemm<300, true><<<ggrid, 256, 0, stream>>>(emb, x, w_ih0, b_ih0, b_hh0, xg);
    lstm_recur<<<BATCH, 448, 0, stream>>>(xg, w_hh0, lengths, hs);

    // Layer 1
    xg_gemm<100, false><<<ggrid, 256, 0, stream>>>(hs, nullptr, w_ih1, b_ih1, b_hh1, xg);
    lstm_recur<<<BATCH, 448, 0, stream>>>(xg, w_hh1, lengths, hs);

    // Layer 2
    xg_gemm<100, false><<<ggrid, 256, 0, stream>>>(hs, nullptr, w_ih2, b_ih2, b_hh2, xg);
    lstm_recur<<<BATCH, 448, 0, stream>>>(xg, w_hh2, lengths, hs);

    // Head
    fc_kernel<<<(BATCH * 3 + 63) / 64, 64, 0, stream>>>(hs, w_fc, b_fc, out);
}

// Round 4
// 3262.615 us; speedup vs baseline: 8.6891x; 8.6891x over previous
//
#include <hip/hip_runtime.h>
#include <hip/hip_bf16.h>

#define T_STEPS 512
#define BATCH   256
#define HID     100
#define GATES   400   // 4*H
#define BT      (BATCH * T_STEPS)

__device__ __forceinline__ float sigm_f(float x) {
    return 1.f / (1.f + __expf(-x));
}

__device__ __forceinline__ float tanh_f(float x) {
    float ax = fabsf(x);
    float t  = __expf(-2.f * ax);
    float r  = (1.f - t) / (1.f + t);
    return copysignf(r, x);
}

// ---------------------------------------------------------------------------
// xg GEMM: out[row, g] = sum_k A[src_row, k] * W[g, k] + b1[g] + b2[g]
// rows = B*T (M=131072), cols = 400 padded to 4 tiles of 128.
// BM=128, BN=128, BK=20. 256 threads, 8x8 microtile, strided ownership:
//   thread rows = row0 + ty + 16*r   (r=0..7)   ty = tid>>4
//   thread cols = col0 + tx + 16*j   (j=0..7)   tx = tid&15
// Live regs: acc 64 + a4 32 + b4 4 + addr ~15 -> ~115 VGPR.
// NO min-waves hint: rounds 1-3 proved any allocator cap below the live set
// spills the accumulators into scratch (6.6/19/30 GB of HBM write traffic).
// ---------------------------------------------------------------------------
template <int K, bool GATHER>
__global__ __launch_bounds__(256) void xg_gemm(
    const float* __restrict__ A, const int* __restrict__ idx,
    const float* __restrict__ W, const float* __restrict__ b1,
    const float* __restrict__ b2, float* __restrict__ out)
{
    __shared__ float As[128][20];
    __shared__ float Bs[128][20];
    __shared__ int   idx_s[128];

    const int tid  = threadIdx.x;
    const int tx   = tid & 15;
    const int ty   = tid >> 4;
    const int row0 = blockIdx.x * 128;
    const int col0 = blockIdx.y * 128;

    if (GATHER) {
        if (tid < 128) idx_s[tid] = idx[row0 + tid];
    }

    float acc[8][8];
#pragma unroll
    for (int r = 0; r < 8; ++r)
#pragma unroll
        for (int j = 0; j < 8; ++j) acc[r][j] = 0.f;

#pragma unroll 1
    for (int k0 = 0; k0 < K; k0 += 20) {
        __syncthreads();
        // stage A tile: 128 rows x 20 floats = 640 float4
        for (int e = tid; e < 640; e += 256) {
            int r = e / 5, kq = e % 5;
            int src_row = GATHER ? idx_s[r] : (row0 + r);
            float4 v = *(const float4*)(A + (size_t)src_row * K + k0 + kq * 4);
            *(float4*)(&As[r][kq * 4]) = v;
        }
        // stage W tile: 128 gate-rows x 20 floats, guard rows >= 400
        for (int e = tid; e < 640; e += 256) {
            int r = e / 5, kq = e % 5;
            int wrow = col0 + r;
            float4 v = make_float4(0.f, 0.f, 0.f, 0.f);
            if (wrow < GATES)
                v = *(const float4*)(W + (size_t)wrow * K + k0 + kq * 4);
            *(float4*)(&Bs[r][kq * 4]) = v;
        }
        __syncthreads();

#pragma unroll
        for (int kk = 0; kk < 20; kk += 4) {
            float4 a4[8];
#pragma unroll
            for (int r = 0; r < 8; ++r)
                a4[r] = *(const float4*)(&As[ty + 16 * r][kk]);
#pragma unroll
            for (int j = 0; j < 8; ++j) {
                float4 b4 = *(const float4*)(&Bs[tx + 16 * j][kk]);
#pragma unroll
                for (int r = 0; r < 8; ++r) {
                    acc[r][j] += a4[r].x * b4.x + a4[r].y * b4.y +
                                 a4[r].z * b4.z + a4[r].w * b4.w;
                }
            }
        }
    }

    // epilogue: bias + guarded store
    float bias[8];
#pragma unroll
    for (int j = 0; j < 8; ++j) {
        int col = col0 + tx + 16 * j;
        bias[j] = (col < GATES) ? (b1[col] + b2[col]) : 0.f;
    }
#pragma unroll
    for (int r = 0; r < 8; ++r) {
        int row = row0 + ty + 16 * r;
#pragma unroll
        for (int j = 0; j < 8; ++j) {
            int col = col0 + tx + 16 * j;
            if (col < GATES)
                out[(size_t)row * GATES + col] = acc[r][j] + bias[j];
        }
    }
}

// ---------------------------------------------------------------------------
// Recurrent scan for one layer. One block per batch element; 448 threads,
// threads g<400 each own one gate row of W_hh (100 floats in VGPRs).
// ---------------------------------------------------------------------------
__global__ __launch_bounds__(448) void lstm_recur(
    const float* __restrict__ xg,    // [B, T, 400]
    const float* __restrict__ w_hh,  // [400, 100]
    const int*   __restrict__ lengths,
    float* __restrict__ hs)          // [B, T, 100]
{
    const int b = blockIdx.x;
    const int g = threadIdx.x;

    __shared__ float h_s[HID];
    __shared__ float gate_s[GATES];

    float w[HID];
    if (g < GATES) {
#pragma unroll
        for (int k = 0; k < HID; k += 4) {
            float4 t = *(const float4*)(w_hh + (size_t)g * HID + k);
            w[k] = t.x; w[k + 1] = t.y; w[k + 2] = t.z; w[k + 3] = t.w;
        }
    }
    if (g < HID) h_s[g] = 0.f;
    float c_reg = 0.f;
    float h_reg = 0.f;

    const int len = lengths[b];
    const float* xgb = xg + (size_t)b * T_STEPS * GATES;
    float*       hsb = hs + (size_t)b * T_STEPS * HID;

    float xg_cur = (g < GATES) ? xgb[g] : 0.f;
    __syncthreads();

    for (int t = 0; t < T_STEPS; ++t) {
        float xg_next = 0.f;
        if (g < GATES && t + 1 < T_STEPS) xg_next = xgb[(size_t)(t + 1) * GATES + g];

        if (g < GATES) {
            float s0 = 0.f, s1 = 0.f, s2 = 0.f, s3 = 0.f;
#pragma unroll
            for (int k = 0; k < HID; k += 4) {
                float4 h4 = *(const float4*)(&h_s[k]);
                s0 += w[k]     * h4.x;
                s1 += w[k + 1] * h4.y;
                s2 += w[k + 2] * h4.z;
                s3 += w[k + 3] * h4.w;
            }
            float pre = xg_cur + ((s0 + s1) + (s2 + s3));
            float a = (g >= 200 && g < 300) ? tanh_f(pre) : sigm_f(pre);
            gate_s[g] = a;
        }
        __syncthreads();
        if (g < HID) {
            float iv = gate_s[g];
            float fv = gate_s[HID + g];
            float gv = gate_s[2 * HID + g];
            float ov = gate_s[3 * HID + g];
            float c_new = fv * c_reg + iv * gv;
            float h_new = ov * tanh_f(c_new);
            bool m = (t < len);
            c_reg = m ? c_new : c_reg;
            h_reg = m ? h_new : h_reg;
            h_s[g] = h_reg;
            hsb[(size_t)t * HID + g] = h_reg;
        }
        xg_cur = xg_next;
        __syncthreads();
    }
}

// ---------------------------------------------------------------------------
// Final linear head
// ---------------------------------------------------------------------------
__global__ __launch_bounds__(64) void fc_kernel(
    const float* __restrict__ hs, const float* __restrict__ w_fc,
    const float* __restrict__ b_fc, float* __restrict__ out)
{
    int tid = blockIdx.x * 64 + threadIdx.x;
    if (tid >= BATCH * 3) return;
    int b = tid / 3, o = tid % 3;
    const float* h = hs + ((size_t)b * T_STEPS + (T_STEPS - 1)) * HID;
    float acc = b_fc[o];
    for (int j = 0; j < HID; ++j) acc += h[j] * w_fc[o * HID + j];
    out[b * 3 + o] = acc;
}

extern "C" void kernel_launch(void* const* d_in, const int* in_sizes, int n_in,
                              void* d_out, int out_size, void* d_ws, size_t ws_size,
                              hipStream_t stream)
{
    const int*   x       = (const int*)  d_in[0];
    const int*   lengths = (const int*)  d_in[1];
    const float* emb     = (const float*)d_in[2];
    const float* w_ih0   = (const float*)d_in[3];
    const float* w_hh0   = (const float*)d_in[4];
    const float* b_ih0   = (const float*)d_in[5];
    const float* b_hh0   = (const float*)d_in[6];
    const float* w_ih1   = (const float*)d_in[7];
    const float* w_hh1   = (const float*)d_in[8];
    const float* b_ih1   = (const float*)d_in[9];
    const float* b_hh1   = (const float*)d_in[10];
    const float* w_ih2   = (const float*)d_in[11];
    const float* w_hh2   = (const float*)d_in[12];
    const float* b_ih2   = (const float*)d_in[13];
    const float* b_hh2   = (const float*)d_in[14];
    const float* w_fc    = (const float*)d_in[15];
    const float* b_fc    = (const float*)d_in[16];
    float* out = (float*)d_out;

    float* xg = (float*)d_ws;                  // [BT, 400]  ~210 MB
    float* hs = xg + (size_t)BT * GATES;       // [BT, 100]  ~52 MB

    dim3 ggrid(BT / 128, 4);

    // Layer 0: embedding gather fused into A-stage, K=300
    xg_gemm<300, true><<<ggrid, 256, 0, stream>>>(emb, x, w_ih0, b_ih0, b_hh0, xg);
    lstm_recur<<<BATCH, 448, 0, stream>>>(xg, w_hh0, lengths, hs);

    // Layer 1
    xg_gemm<100, false><<<ggrid, 256, 0, stream>>>(hs, nullptr, w_ih1, b_ih1, b_hh1, xg);
    lstm_recur<<<BATCH, 448, 0, stream>>>(xg, w_hh1, lengths, hs);

    // Layer 2
    xg_gemm<100, false><<<ggrid, 256, 0, stream>>>(hs, nullptr, w_ih2, b_ih2, b_hh2, xg);
    lstm_recur<<<BATCH, 448, 0, stream>>>(xg, w_hh2, lengths, hs);

    // Head
    fc_kernel<<<(BATCH * 3 + 63) / 64, 64, 0, stream>>>(hs, w_fc, b_fc, out);
}